// Round 5
// baseline (287.939 us; speedup 1.0000x reference)
//
#include <hip/hip_runtime.h>
#include <math.h>

#define D 768
#define DOUT 384
#define LSEQ 512
#define BATCH 4
#define KTOP 51
#define EPS 1e-5f

typedef unsigned short ushort_t;
typedef __bf16 bf16x8 __attribute__((ext_vector_type(8)));
typedef float f32x4 __attribute__((ext_vector_type(4)));

// global->LDS direct DMA, 16B per lane. LDS dest is wave-uniform base + lane*16.
#define GLOAD16(gp, lp)                                                        \
    __builtin_amdgcn_global_load_lds(                                          \
        (const __attribute__((address_space(1))) unsigned int*)(gp),           \
        (__attribute__((address_space(3))) unsigned int*)(lp), 16, 0, 0)

// fp32 -> bf16 round-to-nearest-even (inputs are finite; NaN path not needed)
__device__ __forceinline__ ushort_t f2bf(float f) {
    unsigned int u = __builtin_bit_cast(unsigned int, f);
    u = (u + 0x7FFFu + ((u >> 16) & 1u)) >> 16;
    return (ushort_t)u;
}

// monotone non-decreasing bucket map: u > v  =>  bin(u) >= bin(v).
// Uniform[0,1) input spreads ~1 elem/bin; correctness holds for any input.
__device__ __forceinline__ int binOf(float v) {
    int b = (int)(v * 512.0f);
    return b < 0 ? 0 : (b > 511 ? 511 : b);
}

// ---------------------------------------------------------------------------
// Top-K via histogram selection, O(L) instead of O(L^2) rank scan.
// Selected SET identical to jax.lax.top_k (ties: lower index first) because
// bins are monotone and in-bin ties use the exact (value desc, index asc) rank.
// Output order within the K slots is arbitrary — downstream is order-invariant.
// ---------------------------------------------------------------------------
__global__ __launch_bounds__(256) void topk_kernel(const float* __restrict__ attn,
                                                   int* __restrict__ tk_idx,
                                                   float* __restrict__ tk_val) {
    const int row = blockIdx.x;                 // b*L + l
    const float* a = attn + (size_t)row * LSEQ;
    __shared__ float vals[LSEQ];
    __shared__ int cnt[512];                    // counts -> suffix sums
    __shared__ int thrBin, outSlot;
    const int tid = threadIdx.x;
    const int i1 = tid + 256;

    const float v0 = a[tid];
    const float v1 = a[i1];
    vals[tid] = v0;
    vals[i1] = v1;
    cnt[tid] = 0;
    cnt[i1] = 0;
    if (tid == 0) outSlot = 0;
    __syncthreads();

    const int b0 = binOf(v0);
    const int b1 = binOf(v1);
    atomicAdd(&cnt[b0], 1);
    atomicAdd(&cnt[b1], 1);
    __syncthreads();

    // suffix sum: cnt[b] = #elems with bin >= b  (9 doubling steps)
#pragma unroll
    for (int off = 1; off < 512; off <<= 1) {
        const int t0 = (tid + off < 512) ? cnt[tid + off] : 0;
        const int t1 = (i1 + off < 512) ? cnt[i1 + off] : 0;
        __syncthreads();
        cnt[tid] += t0;
        cnt[i1] += t1;
        __syncthreads();
    }

    // threshold bin T: suffix[T] >= K, suffix[T+1] < K (unique; suffix[0]=512)
    if (cnt[tid] >= KTOP && cnt[tid + 1] < KTOP) thrBin = tid;
    if (cnt[i1] >= KTOP && (i1 == 511 || cnt[i1 + 1] < KTOP)) thrBin = i1;
    __syncthreads();

    const int T = thrBin;
    const int above = (T == 511) ? 0 : cnt[T + 1];
    const int take = KTOP - above;              // >= 1 elems from bin T

#pragma unroll
    for (int e0 = 0; e0 < 2; ++e0) {
        const int e = e0 ? i1 : tid;
        const float v = e0 ? v1 : v0;
        const int bn = e0 ? b1 : b0;
        bool sel = bn > T;
        if (bn == T) {                          // exact rank among bin-T elems
            int r = 0;
            for (int j = 0; j < LSEQ; ++j) {
                const float u = vals[j];
                if (binOf(u) == T && ((u > v) || (u == v && j < e))) r++;
            }
            sel = r < take;
        }
        if (sel) {
            const int slot = atomicAdd(&outSlot, 1);
            tk_idx[row * KTOP + slot] = e;
            tk_val[row * KTOP + slot] = v;
        }
    }
}

// ---------------------------------------------------------------------------
// Prep 1: hidden fp32 (2048x768) -> bf16 row-major. 4 elems/thread.
// ---------------------------------------------------------------------------
__global__ __launch_bounds__(256) void cvt_hidden_kernel(const float* __restrict__ x,
                                                         ushort_t* __restrict__ xb) {
    const int i = (blockIdx.x * 256 + threadIdx.x) * 4;
    const float4 v = *(const float4*)(x + i);
    ushort4 o;
    o.x = f2bf(v.x); o.y = f2bf(v.y); o.z = f2bf(v.z); o.w = f2bf(v.w);
    *(ushort4*)(xb + i) = o;
}

// ---------------------------------------------------------------------------
// Prep 2: W fp32 [k][n] -> WT bf16 [n][k], 32x32 LDS tile transpose.
// ---------------------------------------------------------------------------
__global__ __launch_bounds__(256) void cvt_w_kernel(const float* __restrict__ W0,
                                                    const float* __restrict__ W1,
                                                    ushort_t* __restrict__ WT0,
                                                    ushort_t* __restrict__ WT1) {
    const float* W = blockIdx.z ? W1 : W0;
    ushort_t* WT = blockIdx.z ? WT1 : WT0;
    __shared__ float tile[32][33];
    const int tid = threadIdx.x;
    const int kbase = blockIdx.y * 32;
    const int nbase = blockIdx.x * 32;
    const int r = tid >> 3, c4 = (tid & 7) * 4;

    const float4 v = *(const float4*)(W + (size_t)(kbase + r) * D + nbase + c4);
    tile[r][c4 + 0] = v.x; tile[r][c4 + 1] = v.y; tile[r][c4 + 2] = v.z; tile[r][c4 + 3] = v.w;
    __syncthreads();
    ushort4 o;
    o.x = f2bf(tile[c4 + 0][r]); o.y = f2bf(tile[c4 + 1][r]);
    o.z = f2bf(tile[c4 + 2][r]); o.w = f2bf(tile[c4 + 3][r]);
    *(ushort4*)(WT + (size_t)(nbase + r) * D + kbase + c4) = o;
}

// ---------------------------------------------------------------------------
// Feature GEMM (bf16 MFMA): A(2048x768) @ W(768x768) + bias.
// z==0: W_src -> fsrc_bf (bf16). z==1: W_dst -> feat_dst (fp32).
// ---------------------------------------------------------------------------
__global__ __launch_bounds__(256) void feat_gemm_kernel(const ushort_t* __restrict__ Ah,
                                                        const ushort_t* __restrict__ WT0,
                                                        const float* __restrict__ b0,
                                                        ushort_t* __restrict__ Csrc_bf,
                                                        const ushort_t* __restrict__ WT1,
                                                        const float* __restrict__ b1,
                                                        float* __restrict__ Cdst) {
    const ushort_t* WT = blockIdx.z ? WT1 : WT0;
    const float* bias = blockIdx.z ? b1 : b0;

    __shared__ ushort_t As[128 * 32];
    __shared__ ushort_t Bs[128 * 32];

    const int tid = threadIdx.x;
    const int lane = tid & 63;
    const int wave = tid >> 6;
    const int quad = lane >> 4;
    const int m15 = lane & 15;
    const int qRow = (wave & 1) * 64;
    const int qCol = (wave >> 1) * 64;

    const int rowBase = blockIdx.y * 128;
    const int colBase = blockIdx.x * 128;

    const int e0 = tid * 8;
    const int r0 = e0 >> 5;
    const int c0 = e0 & 31;
    const ushort_t* Abase = Ah + (size_t)rowBase * D;
    const ushort_t* Bbase = WT + (size_t)colBase * D;

    f32x4 acc[4][4] = {};

    for (int kk = 0; kk < D; kk += 32) {
        __syncthreads();
        GLOAD16(Abase + (size_t)r0 * D + kk + c0,        &As[e0]);
        GLOAD16(Abase + (size_t)(r0 + 64) * D + kk + c0, &As[e0 + 2048]);
        GLOAD16(Bbase + (size_t)r0 * D + kk + c0,        &Bs[e0]);
        GLOAD16(Bbase + (size_t)(r0 + 64) * D + kk + c0, &Bs[e0 + 2048]);
        __syncthreads();

        bf16x8 a[4], b[4];
#pragma unroll
        for (int i = 0; i < 4; ++i)
            a[i] = *(const bf16x8*)&As[(qRow + i * 16 + m15) * 32 + quad * 8];
#pragma unroll
        for (int j = 0; j < 4; ++j)
            b[j] = *(const bf16x8*)&Bs[(qCol + j * 16 + m15) * 32 + quad * 8];
#pragma unroll
        for (int i = 0; i < 4; ++i)
#pragma unroll
            for (int j = 0; j < 4; ++j)
                acc[i][j] = __builtin_amdgcn_mfma_f32_16x16x32_bf16(a[i], b[j], acc[i][j], 0, 0, 0);
    }

    // C/D layout: col=lane&15, row=quad*4+reg
    if (blockIdx.z == 0) {
#pragma unroll
        for (int j = 0; j < 4; ++j) {
            const int col = colBase + qCol + j * 16 + m15;
            const float bv = bias[col];
#pragma unroll
            for (int i = 0; i < 4; ++i) {
                ushort_t* Cp = Csrc_bf + (size_t)(rowBase + qRow + i * 16 + quad * 4) * D + col;
#pragma unroll
                for (int r = 0; r < 4; ++r)
                    Cp[(size_t)r * D] = f2bf(acc[i][j][r] + bv);
            }
        }
    } else {
#pragma unroll
        for (int j = 0; j < 4; ++j) {
            const int col = colBase + qCol + j * 16 + m15;
            const float bv = bias[col];
#pragma unroll
            for (int i = 0; i < 4; ++i) {
                float* Cp = Cdst + (size_t)(rowBase + qRow + i * 16 + quad * 4) * D + col;
#pragma unroll
                for (int r = 0; r < 4; ++r)
                    Cp[(size_t)r * D] = acc[i][j][r] + bv;
            }
        }
    }
}

// ---------------------------------------------------------------------------
// Transpose fsrc_bf per batch: (512x768) -> fsrcT (768x512), bf16 32x32 tiles.
// ---------------------------------------------------------------------------
__global__ __launch_bounds__(256) void transpose_fsrc_kernel(const ushort_t* __restrict__ I,
                                                             ushort_t* __restrict__ O) {
    __shared__ ushort_t tile[32][33];
    const int b = blockIdx.z;
    const int cbase = blockIdx.x * 32;   // over D=768
    const int rbase = blockIdx.y * 32;   // over L=512
    const int tid = threadIdx.x;
    const int tr = tid >> 3, tc4 = (tid & 7) * 4;

    const ushort_t* Ib = I + (size_t)b * LSEQ * D;
    ushort_t* Ob = O + (size_t)b * D * LSEQ;

    const ushort4 v = *(const ushort4*)(Ib + (size_t)(rbase + tr) * D + cbase + tc4);
    tile[tr][tc4 + 0] = v.x; tile[tr][tc4 + 1] = v.y;
    tile[tr][tc4 + 2] = v.z; tile[tr][tc4 + 3] = v.w;
    __syncthreads();
    ushort4 o;
    o.x = tile[tc4 + 0][tr]; o.y = tile[tc4 + 1][tr];
    o.z = tile[tc4 + 2][tr]; o.w = tile[tc4 + 3][tr];
    *(ushort4*)(Ob + (size_t)(cbase + tr) * LSEQ + rbase + tc4) = o;
}

// ---------------------------------------------------------------------------
// Score kernel v2: per-lane fd/av slices live in REGISTERS (fixed dims per
// lane across all k). k-loop: one 16B bf16 gather + VALU only.
// ---------------------------------------------------------------------------
__global__ __launch_bounds__(256) void score_kernel(const ushort_t* __restrict__ fsrc_bf,
                                                    const float* __restrict__ feat_dst,
                                                    const float* __restrict__ attn_vec,
                                                    const int* __restrict__ tk_idx,
                                                    const float* __restrict__ tk_val,
                                                    ushort_t* __restrict__ P) {
    const int row = blockIdx.x;     // b*L + l
    const int b = row >> 9;
    const int tid = threadIdx.x;
    const int lane = tid & 63;
    const int wave = tid >> 6;

    __shared__ float sc[KTOP];
    __shared__ int kid[KTOP];
    __shared__ float kvv[KTOP];

    // zero this row of P (512 bf16 = 256 dwords)
    ((unsigned int*)(P + (size_t)row * LSEQ))[tid] = 0u;

    if (tid < KTOP) {
        kid[tid] = tk_idx[row * KTOP + tid];
        kvv[tid] = tk_val[row * KTOP + tid];
    }

    // per-lane register slices: chunk c=lane (all lanes), c=lane+64 (lanes<32)
    const float* fdp = feat_dst + (size_t)row * D;
    float fdr[16], avr[16];
    {
        const int d0 = lane * 8;
        const float4 f0 = *(const float4*)(fdp + d0);
        const float4 f1 = *(const float4*)(fdp + d0 + 4);
        const float4 a0 = *(const float4*)(attn_vec + d0);
        const float4 a1 = *(const float4*)(attn_vec + d0 + 4);
        fdr[0]=f0.x; fdr[1]=f0.y; fdr[2]=f0.z; fdr[3]=f0.w;
        fdr[4]=f1.x; fdr[5]=f1.y; fdr[6]=f1.z; fdr[7]=f1.w;
        avr[0]=a0.x; avr[1]=a0.y; avr[2]=a0.z; avr[3]=a0.w;
        avr[4]=a1.x; avr[5]=a1.y; avr[6]=a1.z; avr[7]=a1.w;
    }
    if (lane < 32) {
        const int d1 = (lane + 64) * 8;
        const float4 f0 = *(const float4*)(fdp + d1);
        const float4 f1 = *(const float4*)(fdp + d1 + 4);
        const float4 a0 = *(const float4*)(attn_vec + d1);
        const float4 a1 = *(const float4*)(attn_vec + d1 + 4);
        fdr[8]=f0.x; fdr[9]=f0.y; fdr[10]=f0.z; fdr[11]=f0.w;
        fdr[12]=f1.x; fdr[13]=f1.y; fdr[14]=f1.z; fdr[15]=f1.w;
        avr[8]=a0.x; avr[9]=a0.y; avr[10]=a0.z; avr[11]=a0.w;
        avr[12]=a1.x; avr[13]=a1.y; avr[14]=a1.z; avr[15]=a1.w;
    }
    __syncthreads();

    for (int k = wave; k < KTOP; k += 4) {
        const ushort_t* g = fsrc_bf + ((size_t)(b << 9) + kid[k]) * D;
        float s = 0.f;
        const bf16x8 g0 = *(const bf16x8*)(g + lane * 8);
#pragma unroll
        for (int jj = 0; jj < 8; ++jj) {
            float x = (float)g0[jj] + fdr[jj];
            x = x > 0.f ? x : 0.2f * x;
            s += x * avr[jj];
        }
        if (lane < 32) {
            const bf16x8 g1 = *(const bf16x8*)(g + (lane + 64) * 8);
#pragma unroll
            for (int jj = 0; jj < 8; ++jj) {
                float x = (float)g1[jj] + fdr[8 + jj];
                x = x > 0.f ? x : 0.2f * x;
                s += x * avr[8 + jj];
            }
        }
#pragma unroll
        for (int off = 32; off > 0; off >>= 1) s += __shfl_down(s, off);
        if (lane == 0) sc[k] = (kvv[k] > 0.f) ? s : -1e9f;
    }
    __syncthreads();

    // softmax over KTOP (wave 0)
    if (wave == 0) {
        float s = (lane < KTOP) ? sc[lane] : -3.0e38f;
        float m = s;
#pragma unroll
        for (int off = 32; off > 0; off >>= 1) m = fmaxf(m, __shfl_xor(m, off));
        float e = (lane < KTOP) ? __expf(s - m) : 0.f;
        float sum = e;
#pragma unroll
        for (int off = 32; off > 0; off >>= 1) sum += __shfl_xor(sum, off);
        if (lane < KTOP) sc[lane] = e / sum;
    }
    __syncthreads();

    // scatter probs into P (indices within a row are distinct)
    if (tid < KTOP)
        P[(size_t)row * LSEQ + kid[tid]] = f2bf(sc[tid]);
}

// ---------------------------------------------------------------------------
// P-GEMM (bf16 MFMA): per batch h' = P_b(512x512) @ fsrc_b(512x768) + gat_bias.
// ---------------------------------------------------------------------------
__global__ __launch_bounds__(256) void pgemm_kernel(const ushort_t* __restrict__ P,
                                                    const ushort_t* __restrict__ fsrcT,
                                                    const float* __restrict__ gat_bias,
                                                    float* __restrict__ hp) {
    const int bb = blockIdx.z;
    const ushort_t* Ab = P + (size_t)bb * LSEQ * LSEQ;
    const ushort_t* Bb = fsrcT + (size_t)bb * D * LSEQ;
    float* Cb = hp + (size_t)bb * LSEQ * D;

    __shared__ ushort_t As[128 * 32];
    __shared__ ushort_t Bs[128 * 32];

    const int tid = threadIdx.x;
    const int lane = tid & 63;
    const int wave = tid >> 6;
    const int quad = lane >> 4;
    const int m15 = lane & 15;
    const int qRow = (wave & 1) * 64;
    const int qCol = (wave >> 1) * 64;

    const int rowBase = blockIdx.y * 128;   // over L=512
    const int colBase = blockIdx.x * 128;   // over D=768

    const int e0 = tid * 8;
    const int r0 = e0 >> 5;
    const int c0 = e0 & 31;
    const ushort_t* Abase = Ab + (size_t)rowBase * LSEQ;
    const ushort_t* Bbase = Bb + (size_t)colBase * LSEQ;

    f32x4 acc[4][4] = {};

    for (int kk = 0; kk < LSEQ; kk += 32) {
        __syncthreads();
        GLOAD16(Abase + (size_t)r0 * LSEQ + kk + c0,        &As[e0]);
        GLOAD16(Abase + (size_t)(r0 + 64) * LSEQ + kk + c0, &As[e0 + 2048]);
        GLOAD16(Bbase + (size_t)r0 * LSEQ + kk + c0,        &Bs[e0]);
        GLOAD16(Bbase + (size_t)(r0 + 64) * LSEQ + kk + c0, &Bs[e0 + 2048]);
        __syncthreads();

        bf16x8 a[4], b[4];
#pragma unroll
        for (int i = 0; i < 4; ++i)
            a[i] = *(const bf16x8*)&As[(qRow + i * 16 + m15) * 32 + quad * 8];
#pragma unroll
        for (int j = 0; j < 4; ++j)
            b[j] = *(const bf16x8*)&Bs[(qCol + j * 16 + m15) * 32 + quad * 8];
#pragma unroll
        for (int i = 0; i < 4; ++i)
#pragma unroll
            for (int j = 0; j < 4; ++j)
                acc[i][j] = __builtin_amdgcn_mfma_f32_16x16x32_bf16(a[i], b[j], acc[i][j], 0, 0, 0);
    }

#pragma unroll
    for (int j = 0; j < 4; ++j) {
        const int col = colBase + qCol + j * 16 + m15;
        const float bv = gat_bias[col];
#pragma unroll
        for (int i = 0; i < 4; ++i) {
            float* Cp = Cb + (size_t)(rowBase + qRow + i * 16 + quad * 4) * D + col;
#pragma unroll
            for (int r = 0; r < 4; ++r)
                Cp[(size_t)r * D] = acc[i][j][r] + bv;
        }
    }
}

// ---------------------------------------------------------------------------
// resgate: h = leaky(h' + hidden, 0.01); gate = h . gate_W + gate_b.
// ---------------------------------------------------------------------------
__global__ __launch_bounds__(256) void resgate_kernel(const float* __restrict__ hp,
                                                      const float* __restrict__ hidden,
                                                      const float* __restrict__ gate_W,
                                                      const float* __restrict__ gate_b,
                                                      float* __restrict__ h_out,
                                                      float* __restrict__ gate_out) {
    const int row = blockIdx.x;
    const int tid = threadIdx.x;
    __shared__ float red[256];

    float gpart = 0.f;
#pragma unroll
    for (int i = 0; i < 3; ++i) {
        const int d = tid + i * 256;
        float hv = hp[(size_t)row * D + d] + hidden[(size_t)row * D + d];
        hv = hv > 0.f ? hv : 0.01f * hv;
        h_out[(size_t)row * D + d] = hv;
        gpart += hv * gate_W[d];
    }
    red[tid] = gpart;
    __syncthreads();
    for (int s = 128; s > 0; s >>= 1) {
        if (tid < s) red[tid] += red[tid + s];
        __syncthreads();
    }
    if (tid == 0) gate_out[row] = red[0] + gate_b[0];
}

// ---------------------------------------------------------------------------
// Final stage (split for parallelism, R1).
// ---------------------------------------------------------------------------
__global__ __launch_bounds__(256) void gatesm_kernel(const float* __restrict__ gate,
                                                     float* __restrict__ p,
                                                     float* __restrict__ pooled,
                                                     float* __restrict__ z) {
    const int b = blockIdx.x;
    const int tid = threadIdx.x;
    __shared__ float red[256];

    const float g0 = gate[b * LSEQ + tid];
    const float g1 = gate[b * LSEQ + tid + 256];
    red[tid] = fmaxf(g0, g1);
    __syncthreads();
    for (int s = 128; s > 0; s >>= 1) { if (tid < s) red[tid] = fmaxf(red[tid], red[tid + s]); __syncthreads(); }
    const float m = red[0];
    __syncthreads();
    const float e0 = __expf(g0 - m), e1 = __expf(g1 - m);
    red[tid] = e0 + e1;
    __syncthreads();
    for (int s = 128; s > 0; s >>= 1) { if (tid < s) red[tid] += red[tid + s]; __syncthreads(); }
    const float inv = 1.f / red[0];
    p[b * LSEQ + tid] = e0 * inv;
    p[b * LSEQ + tid + 256] = e1 * inv;

    for (int d = tid; d < D; d += 256) pooled[b * D + d] = 0.f;
    if (tid < 128) { z[b * DOUT + tid] = 0.f; z[b * DOUT + tid + 128] = 0.f; z[b * DOUT + tid + 256] = 0.f; }
}

__global__ __launch_bounds__(256) void pool_kernel(const float* __restrict__ h,
                                                   const float* __restrict__ p,
                                                   float* __restrict__ pooled) {
    const int b = blockIdx.z;
    const int lbase = blockIdx.y * 64;
    const int d = blockIdx.x * 256 + threadIdx.x;
    const int tid = threadIdx.x;

    __shared__ float ps[64];
    if (tid < 64) ps[tid] = p[b * LSEQ + lbase + tid];
    __syncthreads();

    const float* hb = h + ((size_t)(b * LSEQ + lbase)) * D + d;
    float acc = 0.f;
#pragma unroll 8
    for (int l = 0; l < 64; ++l) {
        acc += ps[l] * hb[(size_t)l * D];
    }
    atomicAdd(&pooled[b * D + d], acc);
}

__global__ __launch_bounds__(256) void ln1_kernel(const float* __restrict__ pooled,
                                                  const float* __restrict__ ln_g,
                                                  const float* __restrict__ ln_b,
                                                  float* __restrict__ y) {
    const int b = blockIdx.x;
    const int tid = threadIdx.x;
    __shared__ float red[256];

    float v[3];
#pragma unroll
    for (int i = 0; i < 3; ++i) v[i] = fmaxf(pooled[b * D + tid + i * 256], 0.f);

    red[tid] = v[0] + v[1] + v[2];
    __syncthreads();
    for (int s = 128; s > 0; s >>= 1) { if (tid < s) red[tid] += red[tid + s]; __syncthreads(); }
    const float mu = red[0] / (float)D;
    __syncthreads();
    float vs = 0.f;
#pragma unroll
    for (int i = 0; i < 3; ++i) { const float dd = v[i] - mu; vs += dd * dd; }
    red[tid] = vs;
    __syncthreads();
    for (int s = 128; s > 0; s >>= 1) { if (tid < s) red[tid] += red[tid + s]; __syncthreads(); }
    const float rstd = rsqrtf(red[0] / (float)D + EPS);
#pragma unroll
    for (int i = 0; i < 3; ++i) {
        const int d = tid + i * 256;
        y[b * D + d] = (v[i] - mu) * rstd * ln_g[d] + ln_b[d];
    }
}

__global__ __launch_bounds__(256) void fc_kernel(const float* __restrict__ y,
                                                 const float* __restrict__ fc_W,
                                                 float* __restrict__ z) {
    const int b = blockIdx.z;
    const int dbase = blockIdx.y * 256;
    const int jbase = blockIdx.x * 64;
    const int tid = threadIdx.x;
    const int jt = tid & 63;
    const int sub = tid >> 6;

    __shared__ float ys[256];
    __shared__ float part[4][64];
    ys[tid] = y[b * D + dbase + tid];
    __syncthreads();

    const float* W = fc_W + (size_t)(dbase + sub * 64) * DOUT + jbase + jt;
    const float* yy = ys + sub * 64;
    float acc = 0.f;
#pragma unroll 8
    for (int i = 0; i < 64; ++i) {
        acc += yy[i] * W[(size_t)i * DOUT];
    }
    part[sub][jt] = acc;
    __syncthreads();
    if (sub == 0) {
        const float tot = part[0][jt] + part[1][jt] + part[2][jt] + part[3][jt];
        atomicAdd(&z[b * DOUT + jbase + jt], tot);
    }
}

__global__ __launch_bounds__(384) void ln2_kernel(const float* __restrict__ z,
                                                  const float* __restrict__ fc_b,
                                                  const float* __restrict__ ln2_g,
                                                  const float* __restrict__ ln2_b,
                                                  float* __restrict__ out) {
    const int b = blockIdx.x;
    const int tid = threadIdx.x;
    const int lane = tid & 63;
    const int wave = tid >> 6;
    __shared__ float wred[6];

    const float v = z[b * DOUT + tid] + fc_b[tid];

    float s = v;
#pragma unroll
    for (int off = 32; off > 0; off >>= 1) s += __shfl_xor(s, off);
    if (lane == 0) wred[wave] = s;
    __syncthreads();
    float mu = 0.f;
#pragma unroll
    for (int w = 0; w < 6; ++w) mu += wred[w];
    mu /= (float)DOUT;
    __syncthreads();

    const float dd = v - mu;
    float s2 = dd * dd;
#pragma unroll
    for (int off = 32; off > 0; off >>= 1) s2 += __shfl_xor(s2, off);
    if (lane == 0) wred[wave] = s2;
    __syncthreads();
    float var = 0.f;
#pragma unroll
    for (int w = 0; w < 6; ++w) var += wred[w];
    const float rstd = rsqrtf(var / (float)DOUT + EPS);

    out[b * DOUT + tid] = dd * rstd * ln2_g[tid] + ln2_b[tid];
}

extern "C" void kernel_launch(void* const* d_in, const int* in_sizes, int n_in,
                              void* d_out, int out_size, void* d_ws, size_t ws_size,
                              hipStream_t stream) {
    const float* hidden   = (const float*)d_in[0];   // (4,512,768)
    const float* attention= (const float*)d_in[1];   // (4,512,512)
    const float* W_src    = (const float*)d_in[2];
    const float* b_src    = (const float*)d_in[3];
    const float* W_dst    = (const float*)d_in[4];
    const float* b_dst    = (const float*)d_in[5];
    const float* attn_vec = (const float*)d_in[6];
    const float* gat_bias = (const float*)d_in[7];
    const float* gate_W   = (const float*)d_in[8];
    const float* gate_b   = (const float*)d_in[9];
    const float* ln_g     = (const float*)d_in[10];
    const float* ln_b     = (const float*)d_in[11];
    const float* fc_W     = (const float*)d_in[12];
    const float* fc_b     = (const float*)d_in[13];
    const float* ln2_g    = (const float*)d_in[14];
    const float* ln2_b    = (const float*)d_in[15];
    float* out = (float*)d_out;

    const int M = BATCH * LSEQ;           // 2048
    float* feat_dst = (float*)d_ws;                       // M*D fp32
    float* hp       = feat_dst + (size_t)M * D;           // M*D fp32 (P@g + gat_bias)
    float* h        = hp + (size_t)M * D;                 // M*D fp32
    float* gate     = h + (size_t)M * D;                  // M
    float* tk_val   = gate + M;                           // M*KTOP
    int*   tk_idx   = (int*)(tk_val + (size_t)M * KTOP);  // M*KTOP
    float* p        = (float*)(tk_idx + (size_t)M * KTOP);// B*LSEQ
    float* pooled   = p + BATCH * LSEQ;                   // B*D
    float* y        = pooled + BATCH * D;                 // B*D
    float* z        = y + BATCH * D;                      // B*DOUT
    ushort_t* Ah    = (ushort_t*)(z + BATCH * DOUT);      // M*D bf16
    ushort_t* WT0   = Ah + (size_t)M * D;                 // D*D bf16 [n][k]
    ushort_t* WT1   = WT0 + (size_t)D * D;                // D*D bf16 [n][k]
    ushort_t* fsrcb = WT1 + (size_t)D * D;                // M*D bf16
    ushort_t* fsrcT = fsrcb + (size_t)M * D;              // M*D bf16 (batch 768x512)
    ushort_t* P     = fsrcT + (size_t)M * D;              // M*LSEQ bf16

    hipLaunchKernelGGL(topk_kernel, dim3(M), dim3(256), 0, stream,
                       attention, tk_idx, tk_val);
    hipLaunchKernelGGL(cvt_hidden_kernel, dim3((M * D) / 1024), dim3(256), 0, stream,
                       hidden, Ah);
    hipLaunchKernelGGL(cvt_w_kernel, dim3(D / 32, D / 32, 2), dim3(256), 0, stream,
                       W_src, W_dst, WT0, WT1);
    hipLaunchKernelGGL(feat_gemm_kernel, dim3(D / 128, M / 128, 2), dim3(256), 0, stream,
                       Ah, WT0, b_src, fsrcb, WT1, b_dst, feat_dst);
    hipLaunchKernelGGL(transpose_fsrc_kernel, dim3(D / 32, LSEQ / 32, BATCH), dim3(256), 0, stream,
                       fsrcb, fsrcT);
    hipLaunchKernelGGL(score_kernel, dim3(M), dim3(256), 0, stream,
                       fsrcb, feat_dst, attn_vec, tk_idx, tk_val, P);
    hipLaunchKernelGGL(pgemm_kernel, dim3(D / 128, LSEQ / 128, BATCH), dim3(256), 0, stream,
                       P, fsrcT, gat_bias, hp);
    hipLaunchKernelGGL(resgate_kernel, dim3(M), dim3(256), 0, stream,
                       hp, hidden, gate_W, gate_b, h, gate);
    hipLaunchKernelGGL(gatesm_kernel, dim3(BATCH), dim3(256), 0, stream,
                       gate, p, pooled, z);
    hipLaunchKernelGGL(pool_kernel, dim3(D / 256, LSEQ / 64, BATCH), dim3(256), 0, stream,
                       h, p, pooled);
    hipLaunchKernelGGL(ln1_kernel, dim3(BATCH), dim3(256), 0, stream,
                       pooled, ln_g, ln_b, y);
    hipLaunchKernelGGL(fc_kernel, dim3(DOUT / 64, D / 256, BATCH), dim3(256), 0, stream,
                       y, fc_W, z);
    hipLaunchKernelGGL(ln2_kernel, dim3(BATCH), dim3(384), 0, stream,
                       z, fc_b, ln2_g, ln2_b, out);
}

// Round 6
// 187.292 us; speedup vs baseline: 1.5374x; 1.5374x over previous
//
#include <hip/hip_runtime.h>
#include <math.h>

#define D 768
#define DOUT 384
#define LSEQ 512
#define BATCH 4
#define KTOP 51
#define EPS 1e-5f

typedef unsigned short ushort_t;
typedef __bf16 bf16x8 __attribute__((ext_vector_type(8)));
typedef float f32x4 __attribute__((ext_vector_type(4)));

// global->LDS direct DMA, 16B per lane. LDS dest is wave-uniform base + lane*16.
#define GLOAD16(gp, lp)                                                        \
    __builtin_amdgcn_global_load_lds(                                          \
        (const __attribute__((address_space(1))) unsigned int*)(gp),           \
        (__attribute__((address_space(3))) unsigned int*)(lp), 16, 0, 0)

// fp32 -> bf16 round-to-nearest-even (inputs are finite; NaN path not needed)
__device__ __forceinline__ ushort_t f2bf(float f) {
    unsigned int u = __builtin_bit_cast(unsigned int, f);
    u = (u + 0x7FFFu + ((u >> 16) & 1u)) >> 16;
    return (ushort_t)u;
}

// ---------------------------------------------------------------------------
// Top-K v3: statistical pre-filter + exact rank on survivors.
// attention ~ Uniform[0,1): #\{v > 0.75\} per row ~ Binomial(512, 0.25),
// mean 128, sigma 10.6 -> 51 <= n_hi <= 320 holds with overwhelming margin.
// When n_hi >= 51 the top-51 are all > 0.75, and their global rank equals
// their rank within the survivor set (lo elements can never beat them), with
// the exact jax tie rule (value desc, index asc). Any other input takes the
// exact full-rank fallback. Barrier-light: 2 syncthreads, no O(L^2) scan.
// ---------------------------------------------------------------------------
__global__ __launch_bounds__(256) void topk_kernel(const float* __restrict__ attn,
                                                   int* __restrict__ tk_idx,
                                                   float* __restrict__ tk_val) {
    const int row = blockIdx.x;                 // b*L + l
    const float* a = attn + (size_t)row * LSEQ;
    __shared__ float vals[LSEQ];
    __shared__ float cval[320];
    __shared__ int cidx[320];
    __shared__ int nhi, outSlot;
    const int tid = threadIdx.x;

    if (tid == 0) { nhi = 0; outSlot = 0; }
    const float v0 = a[tid];
    const float v1 = a[tid + 256];
    vals[tid] = v0;
    vals[tid + 256] = v1;
    __syncthreads();

    const float t = 0.75f;
    if (v0 > t) {
        const int s = atomicAdd(&nhi, 1);
        if (s < 320) { cval[s] = v0; cidx[s] = tid; }
    }
    if (v1 > t) {
        const int s = atomicAdd(&nhi, 1);
        if (s < 320) { cval[s] = v1; cidx[s] = tid + 256; }
    }
    __syncthreads();

    const int n = nhi;
    if (n >= KTOP && n <= 320) {
        // fast path: rank within survivor set (== global rank for survivors)
        if (tid < n) {
            const float v = cval[tid];
            const int e = cidx[tid];
            int r = 0;
            for (int j = 0; j < n; ++j) {
                const float u = cval[j];
                r += (u > v) || (u == v && cidx[j] < e);
            }
            if (r < KTOP) {
                const int s = atomicAdd(&outSlot, 1);
                tk_idx[row * KTOP + s] = e;
                tk_val[row * KTOP + s] = v;
            }
        }
    } else {
        // exact fallback for arbitrary inputs: full O(L^2) rank scan
#pragma unroll
        for (int e0 = 0; e0 < 2; ++e0) {
            const int e = tid + e0 * 256;
            const float v = vals[e];
            int r = 0;
            for (int j = 0; j < LSEQ; ++j) {
                const float u = vals[j];
                r += (u > v) || (u == v && j < e);
            }
            if (r < KTOP) {
                const int s = atomicAdd(&outSlot, 1);
                tk_idx[row * KTOP + s] = e;
                tk_val[row * KTOP + s] = v;
            }
        }
    }
}

// ---------------------------------------------------------------------------
// Prep 1: hidden fp32 (2048x768) -> bf16 row-major. 4 elems/thread.
// ---------------------------------------------------------------------------
__global__ __launch_bounds__(256) void cvt_hidden_kernel(const float* __restrict__ x,
                                                         ushort_t* __restrict__ xb) {
    const int i = (blockIdx.x * 256 + threadIdx.x) * 4;
    const float4 v = *(const float4*)(x + i);
    ushort4 o;
    o.x = f2bf(v.x); o.y = f2bf(v.y); o.z = f2bf(v.z); o.w = f2bf(v.w);
    *(ushort4*)(xb + i) = o;
}

// ---------------------------------------------------------------------------
// Prep 2: W fp32 [k][n] -> WT bf16 [n][k], 32x32 LDS tile transpose.
// ---------------------------------------------------------------------------
__global__ __launch_bounds__(256) void cvt_w_kernel(const float* __restrict__ W0,
                                                    const float* __restrict__ W1,
                                                    ushort_t* __restrict__ WT0,
                                                    ushort_t* __restrict__ WT1) {
    const float* W = blockIdx.z ? W1 : W0;
    ushort_t* WT = blockIdx.z ? WT1 : WT0;
    __shared__ float tile[32][33];
    const int tid = threadIdx.x;
    const int kbase = blockIdx.y * 32;
    const int nbase = blockIdx.x * 32;
    const int r = tid >> 3, c4 = (tid & 7) * 4;

    const float4 v = *(const float4*)(W + (size_t)(kbase + r) * D + nbase + c4);
    tile[r][c4 + 0] = v.x; tile[r][c4 + 1] = v.y; tile[r][c4 + 2] = v.z; tile[r][c4 + 3] = v.w;
    __syncthreads();
    ushort4 o;
    o.x = f2bf(tile[c4 + 0][r]); o.y = f2bf(tile[c4 + 1][r]);
    o.z = f2bf(tile[c4 + 2][r]); o.w = f2bf(tile[c4 + 3][r]);
    *(ushort4*)(WT + (size_t)(nbase + r) * D + kbase + c4) = o;
}

// ---------------------------------------------------------------------------
// Feature GEMM (bf16 MFMA): A(2048x768) @ W(768x768) + bias.
// z==0: W_src -> fsrc_bf (bf16). z==1: W_dst -> feat_dst (fp32).
// ---------------------------------------------------------------------------
__global__ __launch_bounds__(256) void feat_gemm_kernel(const ushort_t* __restrict__ Ah,
                                                        const ushort_t* __restrict__ WT0,
                                                        const float* __restrict__ b0,
                                                        ushort_t* __restrict__ Csrc_bf,
                                                        const ushort_t* __restrict__ WT1,
                                                        const float* __restrict__ b1,
                                                        float* __restrict__ Cdst) {
    const ushort_t* WT = blockIdx.z ? WT1 : WT0;
    const float* bias = blockIdx.z ? b1 : b0;

    __shared__ ushort_t As[128 * 32];
    __shared__ ushort_t Bs[128 * 32];

    const int tid = threadIdx.x;
    const int lane = tid & 63;
    const int wave = tid >> 6;
    const int quad = lane >> 4;
    const int m15 = lane & 15;
    const int qRow = (wave & 1) * 64;
    const int qCol = (wave >> 1) * 64;

    const int rowBase = blockIdx.y * 128;
    const int colBase = blockIdx.x * 128;

    const int e0 = tid * 8;
    const int r0 = e0 >> 5;
    const int c0 = e0 & 31;
    const ushort_t* Abase = Ah + (size_t)rowBase * D;
    const ushort_t* Bbase = WT + (size_t)colBase * D;

    f32x4 acc[4][4] = {};

    for (int kk = 0; kk < D; kk += 32) {
        __syncthreads();
        GLOAD16(Abase + (size_t)r0 * D + kk + c0,        &As[e0]);
        GLOAD16(Abase + (size_t)(r0 + 64) * D + kk + c0, &As[e0 + 2048]);
        GLOAD16(Bbase + (size_t)r0 * D + kk + c0,        &Bs[e0]);
        GLOAD16(Bbase + (size_t)(r0 + 64) * D + kk + c0, &Bs[e0 + 2048]);
        __syncthreads();

        bf16x8 a[4], b[4];
#pragma unroll
        for (int i = 0; i < 4; ++i)
            a[i] = *(const bf16x8*)&As[(qRow + i * 16 + m15) * 32 + quad * 8];
#pragma unroll
        for (int j = 0; j < 4; ++j)
            b[j] = *(const bf16x8*)&Bs[(qCol + j * 16 + m15) * 32 + quad * 8];
#pragma unroll
        for (int i = 0; i < 4; ++i)
#pragma unroll
            for (int j = 0; j < 4; ++j)
                acc[i][j] = __builtin_amdgcn_mfma_f32_16x16x32_bf16(a[i], b[j], acc[i][j], 0, 0, 0);
    }

    // C/D layout: col=lane&15, row=quad*4+reg
    if (blockIdx.z == 0) {
#pragma unroll
        for (int j = 0; j < 4; ++j) {
            const int col = colBase + qCol + j * 16 + m15;
            const float bv = bias[col];
#pragma unroll
            for (int i = 0; i < 4; ++i) {
                ushort_t* Cp = Csrc_bf + (size_t)(rowBase + qRow + i * 16 + quad * 4) * D + col;
#pragma unroll
                for (int r = 0; r < 4; ++r)
                    Cp[(size_t)r * D] = f2bf(acc[i][j][r] + bv);
            }
        }
    } else {
#pragma unroll
        for (int j = 0; j < 4; ++j) {
            const int col = colBase + qCol + j * 16 + m15;
            const float bv = bias[col];
#pragma unroll
            for (int i = 0; i < 4; ++i) {
                float* Cp = Cdst + (size_t)(rowBase + qRow + i * 16 + quad * 4) * D + col;
#pragma unroll
                for (int r = 0; r < 4; ++r)
                    Cp[(size_t)r * D] = acc[i][j][r] + bv;
            }
        }
    }
}

// ---------------------------------------------------------------------------
// Transpose fsrc_bf per batch: (512x768) -> fsrcT (768x512), bf16 32x32 tiles.
// ---------------------------------------------------------------------------
__global__ __launch_bounds__(256) void transpose_fsrc_kernel(const ushort_t* __restrict__ I,
                                                             ushort_t* __restrict__ O) {
    __shared__ ushort_t tile[32][33];
    const int b = blockIdx.z;
    const int cbase = blockIdx.x * 32;   // over D=768
    const int rbase = blockIdx.y * 32;   // over L=512
    const int tid = threadIdx.x;
    const int tr = tid >> 3, tc4 = (tid & 7) * 4;

    const ushort_t* Ib = I + (size_t)b * LSEQ * D;
    ushort_t* Ob = O + (size_t)b * D * LSEQ;

    const ushort4 v = *(const ushort4*)(Ib + (size_t)(rbase + tr) * D + cbase + tc4);
    tile[tr][tc4 + 0] = v.x; tile[tr][tc4 + 1] = v.y;
    tile[tr][tc4 + 2] = v.z; tile[tr][tc4 + 3] = v.w;
    __syncthreads();
    ushort4 o;
    o.x = tile[tc4 + 0][tr]; o.y = tile[tc4 + 1][tr];
    o.z = tile[tc4 + 2][tr]; o.w = tile[tc4 + 3][tr];
    *(ushort4*)(Ob + (size_t)(cbase + tr) * LSEQ + rbase + tc4) = o;
}

// ---------------------------------------------------------------------------
// Score kernel v2: per-lane fd/av slices live in REGISTERS (fixed dims per
// lane across all k). k-loop: one 16B bf16 gather + VALU only.
// ---------------------------------------------------------------------------
__global__ __launch_bounds__(256) void score_kernel(const ushort_t* __restrict__ fsrc_bf,
                                                    const float* __restrict__ feat_dst,
                                                    const float* __restrict__ attn_vec,
                                                    const int* __restrict__ tk_idx,
                                                    const float* __restrict__ tk_val,
                                                    ushort_t* __restrict__ P) {
    const int row = blockIdx.x;     // b*L + l
    const int b = row >> 9;
    const int tid = threadIdx.x;
    const int lane = tid & 63;
    const int wave = tid >> 6;

    __shared__ float sc[KTOP];
    __shared__ int kid[KTOP];
    __shared__ float kvv[KTOP];

    // zero this row of P (512 bf16 = 256 dwords)
    ((unsigned int*)(P + (size_t)row * LSEQ))[tid] = 0u;

    if (tid < KTOP) {
        kid[tid] = tk_idx[row * KTOP + tid];
        kvv[tid] = tk_val[row * KTOP + tid];
    }

    // per-lane register slices: chunk c=lane (all lanes), c=lane+64 (lanes<32)
    const float* fdp = feat_dst + (size_t)row * D;
    float fdr[16], avr[16];
    {
        const int d0 = lane * 8;
        const float4 f0 = *(const float4*)(fdp + d0);
        const float4 f1 = *(const float4*)(fdp + d0 + 4);
        const float4 a0 = *(const float4*)(attn_vec + d0);
        const float4 a1 = *(const float4*)(attn_vec + d0 + 4);
        fdr[0]=f0.x; fdr[1]=f0.y; fdr[2]=f0.z; fdr[3]=f0.w;
        fdr[4]=f1.x; fdr[5]=f1.y; fdr[6]=f1.z; fdr[7]=f1.w;
        avr[0]=a0.x; avr[1]=a0.y; avr[2]=a0.z; avr[3]=a0.w;
        avr[4]=a1.x; avr[5]=a1.y; avr[6]=a1.z; avr[7]=a1.w;
    }
    if (lane < 32) {
        const int d1 = (lane + 64) * 8;
        const float4 f0 = *(const float4*)(fdp + d1);
        const float4 f1 = *(const float4*)(fdp + d1 + 4);
        const float4 a0 = *(const float4*)(attn_vec + d1);
        const float4 a1 = *(const float4*)(attn_vec + d1 + 4);
        fdr[8]=f0.x; fdr[9]=f0.y; fdr[10]=f0.z; fdr[11]=f0.w;
        fdr[12]=f1.x; fdr[13]=f1.y; fdr[14]=f1.z; fdr[15]=f1.w;
        avr[8]=a0.x; avr[9]=a0.y; avr[10]=a0.z; avr[11]=a0.w;
        avr[12]=a1.x; avr[13]=a1.y; avr[14]=a1.z; avr[15]=a1.w;
    }
    __syncthreads();

    for (int k = wave; k < KTOP; k += 4) {
        const ushort_t* g = fsrc_bf + ((size_t)(b << 9) + kid[k]) * D;
        float s = 0.f;
        const bf16x8 g0 = *(const bf16x8*)(g + lane * 8);
#pragma unroll
        for (int jj = 0; jj < 8; ++jj) {
            float x = (float)g0[jj] + fdr[jj];
            x = x > 0.f ? x : 0.2f * x;
            s += x * avr[jj];
        }
        if (lane < 32) {
            const bf16x8 g1 = *(const bf16x8*)(g + (lane + 64) * 8);
#pragma unroll
            for (int jj = 0; jj < 8; ++jj) {
                float x = (float)g1[jj] + fdr[8 + jj];
                x = x > 0.f ? x : 0.2f * x;
                s += x * avr[8 + jj];
            }
        }
#pragma unroll
        for (int off = 32; off > 0; off >>= 1) s += __shfl_down(s, off);
        if (lane == 0) sc[k] = (kvv[k] > 0.f) ? s : -1e9f;
    }
    __syncthreads();

    // softmax over KTOP (wave 0)
    if (wave == 0) {
        float s = (lane < KTOP) ? sc[lane] : -3.0e38f;
        float m = s;
#pragma unroll
        for (int off = 32; off > 0; off >>= 1) m = fmaxf(m, __shfl_xor(m, off));
        float e = (lane < KTOP) ? __expf(s - m) : 0.f;
        float sum = e;
#pragma unroll
        for (int off = 32; off > 0; off >>= 1) sum += __shfl_xor(sum, off);
        if (lane < KTOP) sc[lane] = e / sum;
    }
    __syncthreads();

    // scatter probs into P (indices within a row are distinct)
    if (tid < KTOP)
        P[(size_t)row * LSEQ + kid[tid]] = f2bf(sc[tid]);
}

// ---------------------------------------------------------------------------
// P-GEMM (bf16 MFMA): per batch h' = P_b(512x512) @ fsrc_b(512x768) + gat_bias.
// ---------------------------------------------------------------------------
__global__ __launch_bounds__(256) void pgemm_kernel(const ushort_t* __restrict__ P,
                                                    const ushort_t* __restrict__ fsrcT,
                                                    const float* __restrict__ gat_bias,
                                                    float* __restrict__ hp) {
    const int bb = blockIdx.z;
    const ushort_t* Ab = P + (size_t)bb * LSEQ * LSEQ;
    const ushort_t* Bb = fsrcT + (size_t)bb * D * LSEQ;
    float* Cb = hp + (size_t)bb * LSEQ * D;

    __shared__ ushort_t As[128 * 32];
    __shared__ ushort_t Bs[128 * 32];

    const int tid = threadIdx.x;
    const int lane = tid & 63;
    const int wave = tid >> 6;
    const int quad = lane >> 4;
    const int m15 = lane & 15;
    const int qRow = (wave & 1) * 64;
    const int qCol = (wave >> 1) * 64;

    const int rowBase = blockIdx.y * 128;   // over L=512
    const int colBase = blockIdx.x * 128;   // over D=768

    const int e0 = tid * 8;
    const int r0 = e0 >> 5;
    const int c0 = e0 & 31;
    const ushort_t* Abase = Ab + (size_t)rowBase * LSEQ;
    const ushort_t* Bbase = Bb + (size_t)colBase * LSEQ;

    f32x4 acc[4][4] = {};

    for (int kk = 0; kk < LSEQ; kk += 32) {
        __syncthreads();
        GLOAD16(Abase + (size_t)r0 * LSEQ + kk + c0,        &As[e0]);
        GLOAD16(Abase + (size_t)(r0 + 64) * LSEQ + kk + c0, &As[e0 + 2048]);
        GLOAD16(Bbase + (size_t)r0 * LSEQ + kk + c0,        &Bs[e0]);
        GLOAD16(Bbase + (size_t)(r0 + 64) * LSEQ + kk + c0, &Bs[e0 + 2048]);
        __syncthreads();

        bf16x8 a[4], b[4];
#pragma unroll
        for (int i = 0; i < 4; ++i)
            a[i] = *(const bf16x8*)&As[(qRow + i * 16 + m15) * 32 + quad * 8];
#pragma unroll
        for (int j = 0; j < 4; ++j)
            b[j] = *(const bf16x8*)&Bs[(qCol + j * 16 + m15) * 32 + quad * 8];
#pragma unroll
        for (int i = 0; i < 4; ++i)
#pragma unroll
            for (int j = 0; j < 4; ++j)
                acc[i][j] = __builtin_amdgcn_mfma_f32_16x16x32_bf16(a[i], b[j], acc[i][j], 0, 0, 0);
    }

#pragma unroll
    for (int j = 0; j < 4; ++j) {
        const int col = colBase + qCol + j * 16 + m15;
        const float bv = gat_bias[col];
#pragma unroll
        for (int i = 0; i < 4; ++i) {
            float* Cp = Cb + (size_t)(rowBase + qRow + i * 16 + quad * 4) * D + col;
#pragma unroll
            for (int r = 0; r < 4; ++r)
                Cp[(size_t)r * D] = acc[i][j][r] + bv;
        }
    }
}

// ---------------------------------------------------------------------------
// resgate: h = leaky(h' + hidden, 0.01); gate = h . gate_W + gate_b.
// ---------------------------------------------------------------------------
__global__ __launch_bounds__(256) void resgate_kernel(const float* __restrict__ hp,
                                                      const float* __restrict__ hidden,
                                                      const float* __restrict__ gate_W,
                                                      const float* __restrict__ gate_b,
                                                      float* __restrict__ h_out,
                                                      float* __restrict__ gate_out) {
    const int row = blockIdx.x;
    const int tid = threadIdx.x;
    __shared__ float red[256];

    float gpart = 0.f;
#pragma unroll
    for (int i = 0; i < 3; ++i) {
        const int d = tid + i * 256;
        float hv = hp[(size_t)row * D + d] + hidden[(size_t)row * D + d];
        hv = hv > 0.f ? hv : 0.01f * hv;
        h_out[(size_t)row * D + d] = hv;
        gpart += hv * gate_W[d];
    }
    red[tid] = gpart;
    __syncthreads();
    for (int s = 128; s > 0; s >>= 1) {
        if (tid < s) red[tid] += red[tid + s];
        __syncthreads();
    }
    if (tid == 0) gate_out[row] = red[0] + gate_b[0];
}

// ---------------------------------------------------------------------------
// Final stage (split for parallelism, R1).
// ---------------------------------------------------------------------------
__global__ __launch_bounds__(256) void gatesm_kernel(const float* __restrict__ gate,
                                                     float* __restrict__ p,
                                                     float* __restrict__ pooled,
                                                     float* __restrict__ z) {
    const int b = blockIdx.x;
    const int tid = threadIdx.x;
    __shared__ float red[256];

    const float g0 = gate[b * LSEQ + tid];
    const float g1 = gate[b * LSEQ + tid + 256];
    red[tid] = fmaxf(g0, g1);
    __syncthreads();
    for (int s = 128; s > 0; s >>= 1) { if (tid < s) red[tid] = fmaxf(red[tid], red[tid + s]); __syncthreads(); }
    const float m = red[0];
    __syncthreads();
    const float e0 = __expf(g0 - m), e1 = __expf(g1 - m);
    red[tid] = e0 + e1;
    __syncthreads();
    for (int s = 128; s > 0; s >>= 1) { if (tid < s) red[tid] += red[tid + s]; __syncthreads(); }
    const float inv = 1.f / red[0];
    p[b * LSEQ + tid] = e0 * inv;
    p[b * LSEQ + tid + 256] = e1 * inv;

    for (int d = tid; d < D; d += 256) pooled[b * D + d] = 0.f;
    if (tid < 128) { z[b * DOUT + tid] = 0.f; z[b * DOUT + tid + 128] = 0.f; z[b * DOUT + tid + 256] = 0.f; }
}

__global__ __launch_bounds__(256) void pool_kernel(const float* __restrict__ h,
                                                   const float* __restrict__ p,
                                                   float* __restrict__ pooled) {
    const int b = blockIdx.z;
    const int lbase = blockIdx.y * 64;
    const int d = blockIdx.x * 256 + threadIdx.x;
    const int tid = threadIdx.x;

    __shared__ float ps[64];
    if (tid < 64) ps[tid] = p[b * LSEQ + lbase + tid];
    __syncthreads();

    const float* hb = h + ((size_t)(b * LSEQ + lbase)) * D + d;
    float acc = 0.f;
#pragma unroll 8
    for (int l = 0; l < 64; ++l) {
        acc += ps[l] * hb[(size_t)l * D];
    }
    atomicAdd(&pooled[b * D + d], acc);
}

__global__ __launch_bounds__(256) void ln1_kernel(const float* __restrict__ pooled,
                                                  const float* __restrict__ ln_g,
                                                  const float* __restrict__ ln_b,
                                                  float* __restrict__ y) {
    const int b = blockIdx.x;
    const int tid = threadIdx.x;
    __shared__ float red[256];

    float v[3];
#pragma unroll
    for (int i = 0; i < 3; ++i) v[i] = fmaxf(pooled[b * D + tid + i * 256], 0.f);

    red[tid] = v[0] + v[1] + v[2];
    __syncthreads();
    for (int s = 128; s > 0; s >>= 1) { if (tid < s) red[tid] += red[tid + s]; __syncthreads(); }
    const float mu = red[0] / (float)D;
    __syncthreads();
    float vs = 0.f;
#pragma unroll
    for (int i = 0; i < 3; ++i) { const float dd = v[i] - mu; vs += dd * dd; }
    red[tid] = vs;
    __syncthreads();
    for (int s = 128; s > 0; s >>= 1) { if (tid < s) red[tid] += red[tid + s]; __syncthreads(); }
    const float rstd = rsqrtf(red[0] / (float)D + EPS);
#pragma unroll
    for (int i = 0; i < 3; ++i) {
        const int d = tid + i * 256;
        y[b * D + d] = (v[i] - mu) * rstd * ln_g[d] + ln_b[d];
    }
}

__global__ __launch_bounds__(256) void fc_kernel(const float* __restrict__ y,
                                                 const float* __restrict__ fc_W,
                                                 float* __restrict__ z) {
    const int b = blockIdx.z;
    const int dbase = blockIdx.y * 256;
    const int jbase = blockIdx.x * 64;
    const int tid = threadIdx.x;
    const int jt = tid & 63;
    const int sub = tid >> 6;

    __shared__ float ys[256];
    __shared__ float part[4][64];
    ys[tid] = y[b * D + dbase + tid];
    __syncthreads();

    const float* W = fc_W + (size_t)(dbase + sub * 64) * DOUT + jbase + jt;
    const float* yy = ys + sub * 64;
    float acc = 0.f;
#pragma unroll 8
    for (int i = 0; i < 64; ++i) {
        acc += yy[i] * W[(size_t)i * DOUT];
    }
    part[sub][jt] = acc;
    __syncthreads();
    if (sub == 0) {
        const float tot = part[0][jt] + part[1][jt] + part[2][jt] + part[3][jt];
        atomicAdd(&z[b * DOUT + jbase + jt], tot);
    }
}

__global__ __launch_bounds__(384) void ln2_kernel(const float* __restrict__ z,
                                                  const float* __restrict__ fc_b,
                                                  const float* __restrict__ ln2_g,
                                                  const float* __restrict__ ln2_b,
                                                  float* __restrict__ out) {
    const int b = blockIdx.x;
    const int tid = threadIdx.x;
    const int lane = tid & 63;
    const int wave = tid >> 6;
    __shared__ float wred[6];

    const float v = z[b * DOUT + tid] + fc_b[tid];

    float s = v;
#pragma unroll
    for (int off = 32; off > 0; off >>= 1) s += __shfl_xor(s, off);
    if (lane == 0) wred[wave] = s;
    __syncthreads();
    float mu = 0.f;
#pragma unroll
    for (int w = 0; w < 6; ++w) mu += wred[w];
    mu /= (float)DOUT;
    __syncthreads();

    const float dd = v - mu;
    float s2 = dd * dd;
#pragma unroll
    for (int off = 32; off > 0; off >>= 1) s2 += __shfl_xor(s2, off);
    if (lane == 0) wred[wave] = s2;
    __syncthreads();
    float var = 0.f;
#pragma unroll
    for (int w = 0; w < 6; ++w) var += wred[w];
    const float rstd = rsqrtf(var / (float)DOUT + EPS);

    out[b * DOUT + tid] = dd * rstd * ln2_g[tid] + ln2_b[tid];
}

extern "C" void kernel_launch(void* const* d_in, const int* in_sizes, int n_in,
                              void* d_out, int out_size, void* d_ws, size_t ws_size,
                              hipStream_t stream) {
    const float* hidden   = (const float*)d_in[0];   // (4,512,768)
    const float* attention= (const float*)d_in[1];   // (4,512,512)
    const float* W_src    = (const float*)d_in[2];
    const float* b_src    = (const float*)d_in[3];
    const float* W_dst    = (const float*)d_in[4];
    const float* b_dst    = (const float*)d_in[5];
    const float* attn_vec = (const float*)d_in[6];
    const float* gat_bias = (const float*)d_in[7];
    const float* gate_W   = (const float*)d_in[8];
    const float* gate_b   = (const float*)d_in[9];
    const float* ln_g     = (const float*)d_in[10];
    const float* ln_b     = (const float*)d_in[11];
    const float* fc_W     = (const float*)d_in[12];
    const float* fc_b     = (const float*)d_in[13];
    const float* ln2_g    = (const float*)d_in[14];
    const float* ln2_b    = (const float*)d_in[15];
    float* out = (float*)d_out;

    const int M = BATCH * LSEQ;           // 2048
    float* feat_dst = (float*)d_ws;                       // M*D fp32
    float* hp       = feat_dst + (size_t)M * D;           // M*D fp32 (P@g + gat_bias)
    float* h        = hp + (size_t)M * D;                 // M*D fp32
    float* gate     = h + (size_t)M * D;                  // M
    float* tk_val   = gate + M;                           // M*KTOP
    int*   tk_idx   = (int*)(tk_val + (size_t)M * KTOP);  // M*KTOP
    float* p        = (float*)(tk_idx + (size_t)M * KTOP);// B*LSEQ
    float* pooled   = p + BATCH * LSEQ;                   // B*D
    float* y        = pooled + BATCH * D;                 // B*D
    float* z        = y + BATCH * D;                      // B*DOUT
    ushort_t* Ah    = (ushort_t*)(z + BATCH * DOUT);      // M*D bf16
    ushort_t* WT0   = Ah + (size_t)M * D;                 // D*D bf16 [n][k]
    ushort_t* WT1   = WT0 + (size_t)D * D;                // D*D bf16 [n][k]
    ushort_t* fsrcb = WT1 + (size_t)D * D;                // M*D bf16
    ushort_t* fsrcT = fsrcb + (size_t)M * D;              // M*D bf16 (batch 768x512)
    ushort_t* P     = fsrcT + (size_t)M * D;              // M*LSEQ bf16

    hipLaunchKernelGGL(topk_kernel, dim3(M), dim3(256), 0, stream,
                       attention, tk_idx, tk_val);
    hipLaunchKernelGGL(cvt_hidden_kernel, dim3((M * D) / 1024), dim3(256), 0, stream,
                       hidden, Ah);
    hipLaunchKernelGGL(cvt_w_kernel, dim3(D / 32, D / 32, 2), dim3(256), 0, stream,
                       W_src, W_dst, WT0, WT1);
    hipLaunchKernelGGL(feat_gemm_kernel, dim3(D / 128, M / 128, 2), dim3(256), 0, stream,
                       Ah, WT0, b_src, fsrcb, WT1, b_dst, feat_dst);
    hipLaunchKernelGGL(transpose_fsrc_kernel, dim3(D / 32, LSEQ / 32, BATCH), dim3(256), 0, stream,
                       fsrcb, fsrcT);
    hipLaunchKernelGGL(score_kernel, dim3(M), dim3(256), 0, stream,
                       fsrcb, feat_dst, attn_vec, tk_idx, tk_val, P);
    hipLaunchKernelGGL(pgemm_kernel, dim3(D / 128, LSEQ / 128, BATCH), dim3(256), 0, stream,
                       P, fsrcT, gat_bias, hp);
    hipLaunchKernelGGL(resgate_kernel, dim3(M), dim3(256), 0, stream,
                       hp, hidden, gate_W, gate_b, h, gate);
    hipLaunchKernelGGL(gatesm_kernel, dim3(BATCH), dim3(256), 0, stream,
                       gate, p, pooled, z);
    hipLaunchKernelGGL(pool_kernel, dim3(D / 256, LSEQ / 64, BATCH), dim3(256), 0, stream,
                       h, p, pooled);
    hipLaunchKernelGGL(ln1_kernel, dim3(BATCH), dim3(256), 0, stream,
                       pooled, ln_g, ln_b, y);
    hipLaunchKernelGGL(fc_kernel, dim3(DOUT / 64, D / 256, BATCH), dim3(256), 0, stream,
                       y, fc_W, z);
    hipLaunchKernelGGL(ln2_kernel, dim3(BATCH), dim3(384), 0, stream,
                       z, fc_b, ln2_g, ln2_b, out);
}